// Round 10
// baseline (136.909 us; speedup 1.0000x reference)
//
#include <hip/hip_runtime.h>

#define BB 8
#define CC 64
#define HH 256
#define WW 256
#define KK 5

// ---------------------------------------------------------------------------
// Stage A: avgpool + 3x dwconv(128^2) + maxpool, QUARTER-plane per block.
// 2048 blocks x 256 threads, LDS 76x84 (25.5 KB -> 6 blocks/CU).
// Buffer row r = pooled row R0-6+r (r=0..75); dword d = pooled col C0-8+d
// relative (p = d-8, p in [-8,76)). All conv reads are 4 aligned b128 (e16);
// slot-XOR swizzle (slot ^= (r>>2)&1) spreads bank-quads across v-parity.
// In-place: conv reads all -> barrier -> writes -> barrier. conv3+maxpool
// fused, stores float4 to t2, no LDS write.
// Tile (v,u): 4 rows x 8 cols. Output col p = 8u-4+j (conv1/2), p = 8u+j
// (conv3). Output row = pooled R0-4+4v+i / R0-2+4v+i / R0+4v+i.
// Stale-halo outputs (fed by unwritten taps) are provably never consumed.
// ---------------------------------------------------------------------------
__device__ __forceinline__ void load_e16(const float* __restrict__ sb,
                                         int r, int sbase, float e[16])
{
    const int bit = (r >> 2) & 1;
    const float* row = sb + r * 84;
#pragma unroll
    for (int m = 0; m < 4; m++) {
        float4 t = *(const float4*)(row + 4 * ((sbase + m) ^ bit));
        e[4 * m + 0] = t.x; e[4 * m + 1] = t.y;
        e[4 * m + 2] = t.z; e[4 * m + 3] = t.w;
    }
}

__global__ __launch_bounds__(256, 6) void k_a(
    const float* __restrict__ x, const float* __restrict__ w1,
    const float* __restrict__ b1, float* __restrict__ t2)
{
    const int plane = blockIdx.x;          // b*64 + c
    const int c = plane & 63;
    const int R0 = blockIdx.y * 64;        // pooled row base
    const int C0 = blockIdx.z * 64;        // pooled col base
    const int tid = threadIdx.x;

    __shared__ __align__(16) float sb[76 * 84];

    const float* xp = x + (size_t)plane * HH * WW;

    // fill: avgpool. item = float2 at d=2j (pooled cols C0-8+2j, +1), 76x40.
#pragma unroll
    for (int k = 0; k < 12; k++) {
        int i = tid + k * 256;
        if (i < 76 * 40) {
            int r = i / 40, j = i % 40;
            int pr = R0 - 6 + r;
            int ic = C0 + 2 * j - 8;       // even; pair (ic, ic+1)
            float2 v = make_float2(0.f, 0.f);
            if ((unsigned)pr < 128u && (unsigned)ic < 128u) {
                const float* p0 = xp + (size_t)(2 * pr) * WW + 2 * ic;
                float4 a0 = *(const float4*)p0;
                float4 a1 = *(const float4*)(p0 + WW);
                v.x = 0.25f * (a0.x + a0.y + a1.x + a1.y);
                v.y = 0.25f * (a0.z + a0.w + a1.z + a1.w);
            }
            int dd = (2 * j) ^ (((r >> 2) & 1) << 2);
            *(float2*)&sb[r * 84 + dd] = v;
        }
    }
    __syncthreads();

    // ---- conv1: 18x9 = 162 tiles; rb = 4v; out pooled rows R0-4+4v+i ----
    {
        float wr[25];
#pragma unroll
        for (int k = 0; k < 25; k++) wr[k] = w1[0 * CC * 25 + c * 25 + k];
        const float bv = b1[0 * CC + c];
        const bool act = tid < 162;
        const int v = tid / 9, u = tid % 9;
        float a[4][8];
#pragma unroll
        for (int i = 0; i < 4; i++)
#pragma unroll
            for (int j = 0; j < 8; j++) a[i][j] = bv;
        if (act) {
#pragma unroll
            for (int ir = 0; ir < 8; ir++) {
                float e[16];
                load_e16(sb, 4 * v + ir, 2 * u, e);
#pragma unroll
                for (int i = 0; i < 4; i++) {
                    const int ky = ir - i;
                    if (ky >= 0 && ky < 5) {
#pragma unroll
                        for (int kx = 0; kx < 5; kx++) {
                            const float wv = wr[ky * 5 + kx];
#pragma unroll
                            for (int j = 0; j < 8; j++) a[i][j] += e[2 + j + kx] * wv;
                        }
                    }
                }
            }
#pragma unroll
            for (int i = 0; i < 4; i++) {
                int gi = R0 - 4 + 4 * v + i;
                bool rok = (unsigned)gi < 128u;
#pragma unroll
                for (int j = 0; j < 8; j++) {
                    int ic = C0 + 8 * u - 4 + j;
                    if (!(rok && (unsigned)ic < 128u)) a[i][j] = 0.f;
                }
            }
        }
        __syncthreads();
        if (act) {
#pragma unroll
            for (int i = 0; i < 4; i++) {
                const int rw = 4 * v + 2 + i;
                const int bit = (rw >> 2) & 1;
                float* row = sb + rw * 84;
                *(float4*)(row + 4 * ((2 * u + 1) ^ bit)) =
                    make_float4(a[i][0], a[i][1], a[i][2], a[i][3]);
                *(float4*)(row + 4 * ((2 * u + 2) ^ bit)) =
                    make_float4(a[i][4], a[i][5], a[i][6], a[i][7]);
            }
        }
        __syncthreads();
    }

    // ---- conv2: 17x9 = 153 tiles; rb = 4v+2; out rows R0-2+4v+i ----
    {
        float wr[25];
#pragma unroll
        for (int k = 0; k < 25; k++) wr[k] = w1[1 * CC * 25 + c * 25 + k];
        const float bv = b1[1 * CC + c];
        const bool act = tid < 153;
        const int v = tid / 9, u = tid % 9;
        float a[4][8];
#pragma unroll
        for (int i = 0; i < 4; i++)
#pragma unroll
            for (int j = 0; j < 8; j++) a[i][j] = bv;
        if (act) {
#pragma unroll
            for (int ir = 0; ir < 8; ir++) {
                float e[16];
                load_e16(sb, 4 * v + 2 + ir, 2 * u, e);
#pragma unroll
                for (int i = 0; i < 4; i++) {
                    const int ky = ir - i;
                    if (ky >= 0 && ky < 5) {
#pragma unroll
                        for (int kx = 0; kx < 5; kx++) {
                            const float wv = wr[ky * 5 + kx];
#pragma unroll
                            for (int j = 0; j < 8; j++) a[i][j] += e[2 + j + kx] * wv;
                        }
                    }
                }
            }
#pragma unroll
            for (int i = 0; i < 4; i++) {
                int gi = R0 - 2 + 4 * v + i;
                bool rok = (unsigned)gi < 128u;
#pragma unroll
                for (int j = 0; j < 8; j++) {
                    int ic = C0 + 8 * u - 4 + j;
                    if (!(rok && (unsigned)ic < 128u)) a[i][j] = 0.f;
                }
            }
        }
        __syncthreads();
        if (act) {
#pragma unroll
            for (int i = 0; i < 4; i++) {
                const int rw = 4 * v + 4 + i;
                const int bit = (rw >> 2) & 1;
                float* row = sb + rw * 84;
                *(float4*)(row + 4 * ((2 * u + 1) ^ bit)) =
                    make_float4(a[i][0], a[i][1], a[i][2], a[i][3]);
                *(float4*)(row + 4 * ((2 * u + 2) ^ bit)) =
                    make_float4(a[i][4], a[i][5], a[i][6], a[i][7]);
            }
        }
        __syncthreads();
    }

    // ---- conv3 + maxpool: 16x8 = 128 tiles; rb = 4v+4; out rows R0+4v+i,
    //      cols p = 8u+j (sbase = 2u+1). 2x2 max -> t2, float4 stores. ----
    {
        float wr[25];
#pragma unroll
        for (int k = 0; k < 25; k++) wr[k] = w1[2 * CC * 25 + c * 25 + k];
        const float bv = b1[2 * CC + c];
        if (tid < 128) {
            const int v = tid >> 3, u = tid & 7;
            float a[4][8];
#pragma unroll
            for (int i = 0; i < 4; i++)
#pragma unroll
                for (int j = 0; j < 8; j++) a[i][j] = bv;
#pragma unroll
            for (int ir = 0; ir < 8; ir++) {
                float e[16];
                load_e16(sb, 4 * v + 4 + ir, 2 * u + 1, e);
#pragma unroll
                for (int i = 0; i < 4; i++) {
                    const int ky = ir - i;
                    if (ky >= 0 && ky < 5) {
#pragma unroll
                        for (int kx = 0; kx < 5; kx++) {
                            const float wv = wr[ky * 5 + kx];
#pragma unroll
                            for (int j = 0; j < 8; j++) a[i][j] += e[2 + j + kx] * wv;
                        }
                    }
                }
            }
            const int PR0 = (R0 >> 1) + 2 * v;
            const int PC0 = (C0 >> 1) + 4 * u;
#pragma unroll
            for (int ii = 0; ii < 2; ii++) {
                float4 o;
                o.x = fmaxf(fmaxf(a[2*ii][0], a[2*ii][1]), fmaxf(a[2*ii+1][0], a[2*ii+1][1]));
                o.y = fmaxf(fmaxf(a[2*ii][2], a[2*ii][3]), fmaxf(a[2*ii+1][2], a[2*ii+1][3]));
                o.z = fmaxf(fmaxf(a[2*ii][4], a[2*ii][5]), fmaxf(a[2*ii+1][4], a[2*ii+1][5]));
                o.w = fmaxf(fmaxf(a[2*ii][6], a[2*ii][7]), fmaxf(a[2*ii+1][6], a[2*ii+1][7]));
                *(float4*)&t2[((size_t)plane * 64 + PR0 + ii) * 64 + PC0] = o;
            }
        }
    }
}

// 2x4 e12 conv (Stage B): 6 rows x 3 float4; outputs at src+(2+i)*SS+4+j.
template<int SS>
__device__ __forceinline__ void conv2x4_e12(const float* __restrict__ src,
                                            const float* __restrict__ wr,
                                            float bv, float a[2][4])
{
#pragma unroll
    for (int i = 0; i < 2; i++)
#pragma unroll
        for (int j = 0; j < 4; j++) a[i][j] = bv;
#pragma unroll
    for (int ir = 0; ir < 6; ir++) {
        const float* s = src + ir * SS;
        float4 A = *(const float4*)s;
        float4 B = *(const float4*)(s + 4);
        float4 C = *(const float4*)(s + 8);
        float e[12] = {A.x, A.y, A.z, A.w, B.x, B.y, B.z, B.w, C.x, C.y, C.z, C.w};
#pragma unroll
        for (int i = 0; i < 2; i++) {
            const int ky = ir - i;
            if (ky >= 0 && ky < 5) {
#pragma unroll
                for (int kx = 0; kx < 5; kx++) {
                    const float wv = wr[ky * 5 + kx];
#pragma unroll
                    for (int j = 0; j < 4; j++) a[i][j] += e[2 + j + kx] * wv;
                }
            }
        }
    }
}

// ---------------------------------------------------------------------------
// Stage B: per-plane 3x dwconv(64^2) + mean on t2. LDS 68x72, in place,
// 512 threads, 2x4 tiles (exact). conv3 -> mean fused.
// ---------------------------------------------------------------------------
__global__ __launch_bounds__(512, 4) void k_b(
    const float* __restrict__ t2, const float* __restrict__ w2,
    const float* __restrict__ b2, float* __restrict__ g)
{
    const int plane = blockIdx.x;
    const int c = plane & 63;
    const int tid = threadIdx.x;

    __shared__ __align__(16) float sb[68 * 72];
    __shared__ float red[8];

    const float* tp = t2 + (size_t)plane * 4096;

#pragma unroll
    for (int k = 0; k < 3; k++) {
        int i = tid + k * 512;
        if (i < 68 * 18) {
            int r = i / 18, q = i % 18;
            float4 v = make_float4(0.f, 0.f, 0.f, 0.f);
            if (r >= 2 && r < 66 && q >= 1 && q <= 16)
                v = *(const float4*)(tp + (size_t)(r - 2) * 64 + 4 * (q - 1));
            *(float4*)&sb[r * 72 + 4 * q] = v;
        }
    }
    __syncthreads();

    const int v = tid >> 4, u = tid & 15;
    const float* rb = &sb[(2 * v) * 72 + 4 * u];
    float* wb = &sb[(2 * v + 2) * 72 + 4 * u + 4];

#pragma unroll
    for (int cv = 0; cv < 2; cv++) {
        float wr[25];
#pragma unroll
        for (int k = 0; k < 25; k++) wr[k] = w2[cv * CC * 25 + c * 25 + k];
        float a[2][4];
        conv2x4_e12<72>(rb, wr, b2[cv * CC + c], a);
        __syncthreads();
#pragma unroll
        for (int i = 0; i < 2; i++)
            *(float4*)(wb + i * 72) = make_float4(a[i][0], a[i][1], a[i][2], a[i][3]);
        __syncthreads();
    }

    float s;
    {
        float wr[25];
#pragma unroll
        for (int k = 0; k < 25; k++) wr[k] = w2[2 * CC * 25 + c * 25 + k];
        float a[2][4];
        conv2x4_e12<72>(rb, wr, b2[2 * CC + c], a);
        s = (a[0][0] + a[0][1] + a[0][2] + a[0][3]) +
            (a[1][0] + a[1][1] + a[1][2] + a[1][3]);
    }
#pragma unroll
    for (int off = 32; off > 0; off >>= 1) s += __shfl_down(s, off);
    if ((tid & 63) == 0) red[tid >> 6] = s;
    __syncthreads();
    if (tid == 0) {
        float t = 0.f;
#pragma unroll
        for (int k = 0; k < 8; k++) t += red[k];
        g[plane] = t * (1.f / 4096.f);
    }
}

// ---------------------------------------------------------------------------
__global__ __launch_bounds__(256) void k_kern(
    const float* __restrict__ g, const float* __restrict__ wk,
    const float* __restrict__ bk, float* __restrict__ kern)
{
    const int o = blockIdx.x * 256 + threadIdx.x;     // 0..12799
    const int b = o / 1600, oo = o - b * 1600;
    float v = bk[oo];
    const float* wp = wk + (size_t)oo * 64;
    const float* gp = g + b * 64;
#pragma unroll 16
    for (int k = 0; k < 64; k++) v += gp[k] * wp[k];
    kern[o] = v;
}

// ---------------------------------------------------------------------------
// Kernel 4: dynamic depthwise conv 5x5, 64x64 tile, 4x4 outputs/thread.
// ---------------------------------------------------------------------------
__global__ __launch_bounds__(256) void k_dyn(
    const float* __restrict__ x, const float* __restrict__ kern,
    const float* __restrict__ bias, float* __restrict__ out)
{
    const int plane = blockIdx.z;
    const int tx = blockIdx.x, ty = blockIdx.y;
    const int tid = threadIdx.x;

    __shared__ __align__(16) float sx[68 * 76];

    const float* xp = x + (size_t)plane * HH * WW;
    const int R0 = ty * 64, C0 = tx * 64;

#pragma unroll
    for (int k = 0; k < 5; k++) {
        int i = tid + k * 256;
        if (i < 68 * 18) {
            int r = i / 18, q = i - r * 18;
            int gr = R0 - 2 + r;
            int gc = C0 - 4 + 4 * q;
            float4 v = make_float4(0.f, 0.f, 0.f, 0.f);
            if ((unsigned)gr < HH && (unsigned)gc < WW)
                v = *(const float4*)(xp + (size_t)gr * WW + gc);
            *(float4*)&sx[r * 76 + 4 * q] = v;
        }
    }

    float w[25];
#pragma unroll
    for (int k = 0; k < 25; k++) w[k] = kern[(size_t)plane * 25 + k];
    const float bv = bias[plane & 63];

    __syncthreads();

    const int tr = (tid >> 4) * 4;
    const int tc = (tid & 15) * 4;
    float acc[4][4];
#pragma unroll
    for (int i = 0; i < 4; i++)
#pragma unroll
        for (int j = 0; j < 4; j++) acc[i][j] = bv;

#pragma unroll
    for (int ir = 0; ir < 8; ir++) {
        const float* s = &sx[(tr + ir) * 76 + tc];
        float4 A = *(const float4*)s;
        float4 B4 = *(const float4*)(s + 4);
        float4 Cv = *(const float4*)(s + 8);
        float e[12] = {A.x, A.y, A.z, A.w, B4.x, B4.y, B4.z, B4.w,
                       Cv.x, Cv.y, Cv.z, Cv.w};
#pragma unroll
        for (int i = 0; i < 4; i++) {
            const int ky = ir - i;
            if (ky >= 0 && ky < 5) {
#pragma unroll
                for (int kx = 0; kx < 5; kx++) {
                    const float wv = w[ky * 5 + kx];
#pragma unroll
                    for (int j = 0; j < 4; j++) acc[i][j] += e[j + kx + 2] * wv;
                }
            }
        }
    }

    float* op = out + (size_t)plane * HH * WW + (size_t)(R0 + tr) * WW + C0 + tc;
#pragma unroll
    for (int i = 0; i < 4; i++)
        *(float4*)(op + (size_t)i * WW) = make_float4(acc[i][0], acc[i][1], acc[i][2], acc[i][3]);
}

// ---------------------------------------------------------------------------
extern "C" void kernel_launch(void* const* d_in, const int* in_sizes, int n_in,
                              void* d_out, int out_size, void* d_ws, size_t ws_size,
                              hipStream_t stream)
{
    const float* x    = (const float*)d_in[0];
    const float* w1   = (const float*)d_in[1];
    const float* b1   = (const float*)d_in[2];
    const float* w2   = (const float*)d_in[3];
    const float* b2   = (const float*)d_in[4];
    const float* wk   = (const float*)d_in[5];
    const float* bk   = (const float*)d_in[6];
    const float* bias = (const float*)d_in[7];
    float* out = (float*)d_out;

    float* ws   = (float*)d_ws;
    float* t2   = ws;                       // 512*64*64 floats
    float* g    = ws + 2097152;             // 512 floats
    float* kern = g + 512;                  // 12800 floats

    k_a<<<dim3(512, 2, 2), 256, 0, stream>>>(x, w1, b1, t2);
    k_b<<<dim3(512), 512, 0, stream>>>(t2, w2, b2, g);
    k_kern<<<dim3(50), 256, 0, stream>>>(g, wk, bk, kern);
    k_dyn<<<dim3(4, 4, 512), 256, 0, stream>>>(x, kern, bias, out);
}